// Round 4
// baseline (430.349 us; speedup 1.0000x reference)
//
#include <hip/hip_runtime.h>
#include <hip/hip_bf16.h>

// b=2, t=4096, emb=512, heads=8, head_dim=64.
// out = softmax((xWq^T)(xWk^T)^T / sqrt(512)) (xWv^T) Wu^T + bu
// Round 3: bisection anchor. Round-0 data paths EXACTLY (qkv/proj verbatim,
// in-kernel V transpose, natural P columns, scalar short P writes, online
// softmax with running max). Only change vs round 0: 64 q-rows per wave
// (4x MFMA amortization of staging/fragment costs), kb/vb hoisted, and an
// explicit barrier between P-write phase and PV-read phase.

#define T 4096
#define HEADS 8
#define HD 64
#define EMB 512
#define BATCH 2
#define BH (BATCH * HEADS)

typedef __attribute__((ext_vector_type(8))) short short8;
typedef __attribute__((ext_vector_type(4))) float floatx4;

// f32 -> bf16 round-to-nearest-even
__device__ inline short f2bf(float f) {
  union { float f; unsigned u; } v; v.f = f;
  unsigned r = v.u + 0x7FFF + ((v.u >> 16) & 1);
  return (short)(r >> 16);
}

__device__ inline short8 pack8(float4 a, float4 b) {
  short8 o;
  o[0] = f2bf(a.x); o[1] = f2bf(a.y); o[2] = f2bf(a.z); o[3] = f2bf(a.w);
  o[4] = f2bf(b.x); o[5] = f2bf(b.y); o[6] = f2bf(b.z); o[7] = f2bf(b.w);
  return o;
}

// swizzled byte offset in a [rows][64] bf16 tile (row stride 128B)
__device__ inline int swz(int row, int byte) {
  return (row * 128 + byte) ^ ((row & 7) << 4);
}

// ---------------------------------------------------------------------------
// Kernel A (round-0 verbatim): q/k/v projections, outputs bf16 [bh][t][d].
// ---------------------------------------------------------------------------
__global__ __launch_bounds__(256) void qkv_kernel(
    const float* __restrict__ x, const float* __restrict__ Wq,
    const float* __restrict__ Wk, const float* __restrict__ Wv,
    short* __restrict__ q_ws, short* __restrict__ k_ws, short* __restrict__ v_ws) {
  __shared__ __align__(16) short xs[256 * 64];
  const int tid = threadIdx.x;
  const int lane = tid & 63;
  const int w = tid >> 6;
  const int g = lane >> 4, lr = lane & 15;
  const long rowbase = (long)blockIdx.x * 256;

  {
    const float4* xv = (const float4*)(x + (rowbase + tid) * 64);
    for (int c = 0; c < 8; ++c) {
      float4 a = xv[2 * c], b = xv[2 * c + 1];
      *(short8*)((char*)xs + swz(tid, c * 16)) = pack8(a, b);
    }
  }
  __syncthreads();

  const float* Ws[3] = {Wq, Wk, Wv};
  short* outs[3] = {q_ws, k_ws, v_ws};
  for (int m = 0; m < 3; ++m) {
    const float* W = Ws[m];
    short* op = outs[m];
    for (int nt = 0; nt < 4; ++nt) {
      const int coln = nt * 16 + lr;
      const float4* wr0 = (const float4*)(W + coln * 64 + 8 * g);
      const float4* wr1 = (const float4*)(W + coln * 64 + 32 + 8 * g);
      short8 b0 = pack8(wr0[0], wr0[1]);
      short8 b1 = pack8(wr1[0], wr1[1]);
      for (int mr = 0; mr < 4; ++mr) {
        const int arow = w * 64 + mr * 16 + lr;
        short8 a0 = *(short8*)((char*)xs + swz(arow, g * 16));
        short8 a1 = *(short8*)((char*)xs + swz(arow, 64 + g * 16));
        floatx4 acc = 0;
        acc = __builtin_amdgcn_mfma_f32_16x16x32_bf16(a0, b0, acc, 0, 0, 0);
        acc = __builtin_amdgcn_mfma_f32_16x16x32_bf16(a1, b1, acc, 0, 0, 0);
        for (int jj = 0; jj < 4; ++jj) {
          long R = rowbase + w * 64 + mr * 16 + 4 * g + jj;
          int bb = (int)(R >> 15);
          int h = (int)(R & 7);
          int t = (int)((R >> 3) & 4095);
          op[(((long)(bb * HEADS + h) * T + t) * 64) + coln] = f2bf(acc[jj]);
        }
      }
    }
  }
}

// ---------------------------------------------------------------------------
// Kernel B: flash attention, online softmax (round-0 math), 64 q-rows/wave.
// Per iter: [stage K,V] sync [kb/vb loads, QK^T, softmax, P writes] sync
//           [pa loads, PV]   (stage(it+1) follows PV; hazards all barriered)
// ---------------------------------------------------------------------------
__global__ __launch_bounds__(256) void attn_kernel(
    const short* __restrict__ q_ws, const short* __restrict__ k_ws,
    const short* __restrict__ v_ws, short* __restrict__ o_ws) {
  __shared__ __align__(16) short Ks[64 * 64];       // [key][d] swizzled
  __shared__ __align__(16) short Vs[64 * 64];       // [d][key] swizzled (transposed here)
  __shared__ __align__(16) short Ps[4][64 * 64];    // per-wave P [row][key] swizzled
  const int tid = threadIdx.x, lane = tid & 63, w = tid >> 6;
  const int g = lane >> 4, lr = lane & 15;
  const int bh = blockIdx.y;
  const int q0 = blockIdx.x * 256;
  const short* Qp = q_ws + (long)bh * T * 64;
  const short* Kp = k_ws + (long)bh * T * 64;
  const short* Vp = v_ws + (long)bh * T * 64;
  short* Pw = (short*)Ps[w];

  const float c2 = 0.0441941738241592f * 1.4426950408889634f;  // scale * log2(e)

  // Q fragments: 4 row-tiles x 2 k-halves, registers for the whole loop
  short8 aq[4][2];
#pragma unroll
  for (int mt = 0; mt < 4; ++mt) {
    int r = q0 + w * 64 + mt * 16 + lr;
    aq[mt][0] = *(const short8*)(Qp + (long)r * 64 + g * 8);
    aq[mt][1] = *(const short8*)(Qp + (long)r * 64 + 32 + g * 8);
  }

  floatx4 acc[4][4];  // [mt][dt]
#pragma unroll
  for (int mt = 0; mt < 4; ++mt)
#pragma unroll
    for (int dt = 0; dt < 4; ++dt) acc[mt][dt] = 0;
  float m2[4][4], ell[4][4];
#pragma unroll
  for (int mt = 0; mt < 4; ++mt)
#pragma unroll
    for (int j = 0; j < 4; ++j) { m2[mt][j] = -1e30f; ell[mt][j] = 0.f; }

  for (int kv = 0; kv < T; kv += 64) {
    // ---- stage K tile [key][d] (round-0 pattern) ----
    {
      int key = tid >> 2, dp = (tid & 3) * 16;
      const short8* src = (const short8*)(Kp + (long)(kv + key) * 64 + dp);
      short8 v0 = src[0], v1 = src[1];
      *(short8*)((char*)Ks + swz(key, dp * 2)) = v0;
      *(short8*)((char*)Ks + swz(key, dp * 2 + 16)) = v1;
    }
    // ---- stage V tile transposed -> Vs[d][key] (round-0 pattern) ----
    {
      int key = lane, dp = w * 16;
      const short8* src = (const short8*)(Vp + (long)(kv + key) * 64 + dp);
      short8 v0 = src[0], v1 = src[1];
#pragma unroll
      for (int jj = 0; jj < 8; ++jj) {
        *(short*)((char*)Vs + swz(dp + jj, key * 2)) = v0[jj];
        *(short*)((char*)Vs + swz(dp + 8 + jj, key * 2)) = v1[jj];
      }
    }
    __syncthreads();

    // ---- fragment loads (shared across the 4 row-tiles) ----
    short8 kb[4][2], vb[4][2];
#pragma unroll
    for (int kt = 0; kt < 4; ++kt) {
      kb[kt][0] = *(short8*)((char*)Ks + swz(kt * 16 + lr, g * 16));
      kb[kt][1] = *(short8*)((char*)Ks + swz(kt * 16 + lr, 64 + g * 16));
    }
#pragma unroll
    for (int dt = 0; dt < 4; ++dt) {
      vb[dt][0] = *(short8*)((char*)Vs + swz(dt * 16 + lr, g * 16));
      vb[dt][1] = *(short8*)((char*)Vs + swz(dt * 16 + lr, 64 + g * 16));
    }

    // ---- QK^T + online softmax + P writes (round-0 math, 4 row-tiles) ----
#pragma unroll
    for (int mt = 0; mt < 4; ++mt) {
      floatx4 s[4];
#pragma unroll
      for (int kt = 0; kt < 4; ++kt) {
        floatx4 z = 0;
        z = __builtin_amdgcn_mfma_f32_16x16x32_bf16(aq[mt][0], kb[kt][0], z, 0, 0, 0);
        z = __builtin_amdgcn_mfma_f32_16x16x32_bf16(aq[mt][1], kb[kt][1], z, 0, 0, 0);
        s[kt] = z;
      }
#pragma unroll
      for (int j = 0; j < 4; ++j) {
        float tm = fmaxf(fmaxf(s[0][j], s[1][j]), fmaxf(s[2][j], s[3][j]));
        for (int off = 8; off >= 1; off >>= 1)
          tm = fmaxf(tm, __shfl_xor(tm, off, 16));
        float mn = fmaxf(m2[mt][j], tm * c2);
        float cf = __builtin_amdgcn_exp2f(m2[mt][j] - mn);
        m2[mt][j] = mn;
        float ts = 0.f;
#pragma unroll
        for (int kt = 0; kt < 4; ++kt) {
          float p = __builtin_amdgcn_exp2f(s[kt][j] * c2 - mn);
          ts += p;
          *(short*)((char*)Pw + swz(mt * 16 + 4 * g + j, (kt * 16 + lr) * 2)) = f2bf(p);
        }
        for (int off = 8; off >= 1; off >>= 1)
          ts += __shfl_xor(ts, off, 16);
        ell[mt][j] = ell[mt][j] * cf + ts;
#pragma unroll
        for (int dt = 0; dt < 4; ++dt) acc[mt][dt][j] *= cf;
      }
    }
    __syncthreads();  // P writes (all lanes) before pa reads

    // ---- PV ----
#pragma unroll
    for (int mt = 0; mt < 4; ++mt) {
      short8 pa0 = *(short8*)((char*)Pw + swz(mt * 16 + lr, g * 16));
      short8 pa1 = *(short8*)((char*)Pw + swz(mt * 16 + lr, 64 + g * 16));
#pragma unroll
      for (int dt = 0; dt < 4; ++dt) {
        acc[mt][dt] = __builtin_amdgcn_mfma_f32_16x16x32_bf16(pa0, vb[dt][0], acc[mt][dt], 0, 0, 0);
        acc[mt][dt] = __builtin_amdgcn_mfma_f32_16x16x32_bf16(pa1, vb[dt][1], acc[mt][dt], 0, 0, 0);
      }
    }
    // next iteration's stage writes Ks/Vs (read-done before last sync) and
    // its P writes come after the next sync — all hazards barrier-separated.
  }

  // epilogue: O[b][t][h*64+d] bf16 (ell fully reduced each iteration)
  const int bb = bh >> 3, h = bh & 7;
#pragma unroll
  for (int mt = 0; mt < 4; ++mt) {
#pragma unroll
    for (int j = 0; j < 4; ++j) {
      float rl = 1.0f / ell[mt][j];
      int trow = q0 + w * 64 + mt * 16 + 4 * g + j;
      long ob = ((long)(bb * T + trow)) * EMB + h * 64;
#pragma unroll
      for (int dt = 0; dt < 4; ++dt)
        o_ws[ob + dt * 16 + lr] = f2bf(acc[mt][dt][j] * rl);
    }
  }
}

// ---------------------------------------------------------------------------
// Kernel C (round-0 verbatim): out[8192][512] = O @ Wu^T + bu (f32 out)
// ---------------------------------------------------------------------------
__global__ __launch_bounds__(256) void proj_kernel(
    const short* __restrict__ o_ws, const float* __restrict__ Wu,
    const float* __restrict__ bu, float* __restrict__ out) {
  __shared__ __align__(16) short As[64 * 64];
  __shared__ __align__(16) short Bs[64 * 64];
  const int tid = threadIdx.x;
  const int lane = tid & 63, w = tid >> 6;
  const int g = lane >> 4, lr = lane & 15;
  const int m0 = blockIdx.x * 64;
  const int n0 = blockIdx.y * 64;

  floatx4 acc[4];
  for (int nt = 0; nt < 4; ++nt) acc[nt] = 0;

  for (int kc = 0; kc < EMB; kc += 64) {
    {
      int row = tid >> 2, kp = (tid & 3) * 16;
      const short8* src = (const short8*)(o_ws + (long)(m0 + row) * EMB + kc + kp);
      short8 v0 = src[0], v1 = src[1];
      *(short8*)((char*)As + swz(row, kp * 2)) = v0;
      *(short8*)((char*)As + swz(row, kp * 2 + 16)) = v1;
    }
    {
      int n = tid >> 2, kp = (tid & 3) * 16;
      const float4* src = (const float4*)(Wu + (long)(n0 + n) * EMB + kc + kp);
      *(short8*)((char*)Bs + swz(n, kp * 2)) = pack8(src[0], src[1]);
      *(short8*)((char*)Bs + swz(n, kp * 2 + 16)) = pack8(src[2], src[3]);
    }
    __syncthreads();

    int arow = w * 16 + lr;
    short8 a0 = *(short8*)((char*)As + swz(arow, g * 16));
    short8 a1 = *(short8*)((char*)As + swz(arow, 64 + g * 16));
    for (int nt = 0; nt < 4; ++nt) {
      int n = nt * 16 + lr;
      short8 b0 = *(short8*)((char*)Bs + swz(n, g * 16));
      short8 b1 = *(short8*)((char*)Bs + swz(n, 64 + g * 16));
      acc[nt] = __builtin_amdgcn_mfma_f32_16x16x32_bf16(a0, b0, acc[nt], 0, 0, 0);
      acc[nt] = __builtin_amdgcn_mfma_f32_16x16x32_bf16(a1, b1, acc[nt], 0, 0, 0);
    }
    __syncthreads();
  }

  for (int nt = 0; nt < 4; ++nt) {
    float bias = bu[n0 + nt * 16 + lr];
    for (int j = 0; j < 4; ++j) {
      int mrow = m0 + w * 16 + 4 * g + j;
      out[(long)mrow * EMB + n0 + nt * 16 + lr] = acc[nt][j] + bias;
    }
  }
}

extern "C" void kernel_launch(void* const* d_in, const int* in_sizes, int n_in,
                              void* d_out, int out_size, void* d_ws, size_t ws_size,
                              hipStream_t stream) {
  const float* x  = (const float*)d_in[0];
  const float* Wq = (const float*)d_in[1];
  const float* Wk = (const float*)d_in[2];
  const float* Wv = (const float*)d_in[3];
  const float* Wu = (const float*)d_in[4];
  const float* bu = (const float*)d_in[5];
  float* out = (float*)d_out;

  const long per = (long)BH * T * 64;
  short* q_ws = (short*)d_ws;
  short* k_ws = q_ws + per;
  short* v_ws = k_ws + per;
  short* o_ws = v_ws + per;  // [8192][512] bf16

  qkv_kernel<<<256, 256, 0, stream>>>(x, Wq, Wk, Wv, q_ws, k_ws, v_ws);
  attn_kernel<<<dim3(T / 256, BH), 256, 0, stream>>>(q_ws, k_ws, v_ws, o_ws);
  proj_kernel<<<dim3(BATCH * T / 64, EMB / 64), 256, 0, stream>>>(o_ws, Wu, bu, out);
}

// Round 5
// 235.470 us; speedup vs baseline: 1.8276x; 1.8276x over previous
//
#include <hip/hip_runtime.h>
#include <hip/hip_bf16.h>

// b=2, t=4096, emb=512, heads=8, head_dim=64.
// out = softmax((xWq^T)(xWk^T)^T / sqrt(512)) (xWv^T) Wu^T + bu
// Round 4: fix occupancy (32 q-rows/wave, 128/block, 512 blocks = 2/CU),
// V transposed in qkv (vt[bh][d][t], no permutation) so attn V-staging is
// b128 copies, per-lane ell partials (epilogue-only reduce). Online softmax,
// scalar P writes, P barrier — all from the round-3 passing anchor.

#define T 4096
#define HEADS 8
#define HD 64
#define EMB 512
#define BATCH 2
#define BH (BATCH * HEADS)

typedef __attribute__((ext_vector_type(8))) short short8;
typedef __attribute__((ext_vector_type(4))) float floatx4;

// f32 -> bf16 round-to-nearest-even
__device__ inline short f2bf(float f) {
  union { float f; unsigned u; } v; v.f = f;
  unsigned r = v.u + 0x7FFF + ((v.u >> 16) & 1);
  return (short)(r >> 16);
}

__device__ inline short8 pack8(float4 a, float4 b) {
  short8 o;
  o[0] = f2bf(a.x); o[1] = f2bf(a.y); o[2] = f2bf(a.z); o[3] = f2bf(a.w);
  o[4] = f2bf(b.x); o[5] = f2bf(b.y); o[6] = f2bf(b.z); o[7] = f2bf(b.w);
  return o;
}

// swizzled byte offset in a [rows][64] bf16 tile (row stride 128B)
__device__ inline int swz(int row, int byte) {
  return (row * 128 + byte) ^ ((row & 7) << 4);
}

// ---------------------------------------------------------------------------
// Kernel A: q/k/v projections. q,k -> [bh][t][d] bf16 (round-0 path).
// v -> vt[bh][d][t] bf16 (transposed at store; each 64B line of vt is
// completed by one block -> L2 write-combining keeps HBM traffic at 8.4MB).
// ---------------------------------------------------------------------------
__global__ __launch_bounds__(256) void qkv_kernel(
    const float* __restrict__ x, const float* __restrict__ Wq,
    const float* __restrict__ Wk, const float* __restrict__ Wv,
    short* __restrict__ q_ws, short* __restrict__ k_ws, short* __restrict__ vt_ws) {
  __shared__ __align__(16) short xs[256 * 64];
  const int tid = threadIdx.x;
  const int lane = tid & 63;
  const int w = tid >> 6;
  const int g = lane >> 4, lr = lane & 15;
  const long rowbase = (long)blockIdx.x * 256;

  {
    const float4* xv = (const float4*)(x + (rowbase + tid) * 64);
    for (int c = 0; c < 8; ++c) {
      float4 a = xv[2 * c], b = xv[2 * c + 1];
      *(short8*)((char*)xs + swz(tid, c * 16)) = pack8(a, b);
    }
  }
  __syncthreads();

  const float* Ws[3] = {Wq, Wk, Wv};
  for (int m = 0; m < 3; ++m) {
    const float* W = Ws[m];
    for (int nt = 0; nt < 4; ++nt) {
      const int coln = nt * 16 + lr;
      const float4* wr0 = (const float4*)(W + coln * 64 + 8 * g);
      const float4* wr1 = (const float4*)(W + coln * 64 + 32 + 8 * g);
      short8 b0 = pack8(wr0[0], wr0[1]);
      short8 b1 = pack8(wr1[0], wr1[1]);
      for (int mr = 0; mr < 4; ++mr) {
        const int arow = w * 64 + mr * 16 + lr;
        short8 a0 = *(short8*)((char*)xs + swz(arow, g * 16));
        short8 a1 = *(short8*)((char*)xs + swz(arow, 64 + g * 16));
        floatx4 acc = 0;
        acc = __builtin_amdgcn_mfma_f32_16x16x32_bf16(a0, b0, acc, 0, 0, 0);
        acc = __builtin_amdgcn_mfma_f32_16x16x32_bf16(a1, b1, acc, 0, 0, 0);
        for (int jj = 0; jj < 4; ++jj) {
          long R = rowbase + w * 64 + mr * 16 + 4 * g + jj;
          int bb = (int)(R >> 15);
          int h = (int)(R & 7);
          int t = (int)((R >> 3) & 4095);
          if (m == 0)
            q_ws[(((long)(bb * HEADS + h) * T + t) * 64) + coln] = f2bf(acc[jj]);
          else if (m == 1)
            k_ws[(((long)(bb * HEADS + h) * T + t) * 64) + coln] = f2bf(acc[jj]);
          else
            vt_ws[((long)(bb * HEADS + h) * 64 + coln) * T + t] = f2bf(acc[jj]);
        }
      }
    }
  }
}

// ---------------------------------------------------------------------------
// Kernel B: flash attention, online softmax, 32 q-rows/wave, 128 rows/block,
// grid 512 = 2 blocks/CU. KV tiles of 64; V staged via b128 from vt.
// Per iter: [stage K,V] sync [kb/vb, QK^T, softmax, P writes] sync [pa, PV].
// ---------------------------------------------------------------------------
__global__ __launch_bounds__(256) void attn_kernel(
    const short* __restrict__ q_ws, const short* __restrict__ k_ws,
    const short* __restrict__ vt_ws, short* __restrict__ o_ws) {
  __shared__ __align__(16) short Ks[64 * 64];       // [key][d] swizzled
  __shared__ __align__(16) short Vs[64 * 64];       // [d][key] swizzled
  __shared__ __align__(16) short Ps[4][32 * 64];    // per-wave P [row][key] swizzled
  const int tid = threadIdx.x, lane = tid & 63, w = tid >> 6;
  const int g = lane >> 4, lr = lane & 15;
  const int bh = blockIdx.y;
  const int q0 = blockIdx.x * 128;
  const short* Qp = q_ws + (long)bh * T * 64;
  const short* Kp = k_ws + (long)bh * T * 64;
  const short* Vt = vt_ws + (long)bh * 64 * T;
  short* Pw = (short*)Ps[w];

  const float c2 = 0.0441941738241592f * 1.4426950408889634f;  // scale * log2(e)

  // Q fragments: 2 row-tiles x 2 k-halves, registers for the whole loop
  short8 aq[2][2];
#pragma unroll
  for (int mt = 0; mt < 2; ++mt) {
    int r = q0 + w * 32 + mt * 16 + lr;
    aq[mt][0] = *(const short8*)(Qp + (long)r * 64 + g * 8);
    aq[mt][1] = *(const short8*)(Qp + (long)r * 64 + 32 + g * 8);
  }

  floatx4 acc[2][4];  // [mt][dt]
#pragma unroll
  for (int mt = 0; mt < 2; ++mt)
#pragma unroll
    for (int dt = 0; dt < 4; ++dt) acc[mt][dt] = 0;
  float m2[2][4], ellp[2][4];  // running max, per-lane partial sums
#pragma unroll
  for (int mt = 0; mt < 2; ++mt)
#pragma unroll
    for (int j = 0; j < 4; ++j) { m2[mt][j] = -1e30f; ellp[mt][j] = 0.f; }

  const int srow = tid >> 2;          // 0..63
  const int sseg = (tid & 3) * 16;    // element offset in row

  for (int kv = 0; kv < T; kv += 64) {
    // ---- stage K tile [key][d] and V tile [d][key] (both b128 copies) ----
    {
      const short8* ksrc = (const short8*)(Kp + (long)(kv + srow) * 64 + sseg);
      short8 k0 = ksrc[0], k1 = ksrc[1];
      const short8* vsrc = (const short8*)(Vt + (long)srow * T + kv + sseg);
      short8 v0 = vsrc[0], v1 = vsrc[1];
      *(short8*)((char*)Ks + swz(srow, sseg * 2)) = k0;
      *(short8*)((char*)Ks + swz(srow, sseg * 2 + 16)) = k1;
      *(short8*)((char*)Vs + swz(srow, sseg * 2)) = v0;
      *(short8*)((char*)Vs + swz(srow, sseg * 2 + 16)) = v1;
    }
    __syncthreads();

    // ---- fragment loads (shared across the 2 row-tiles) ----
    short8 kb[4][2], vb[4][2];
#pragma unroll
    for (int kt = 0; kt < 4; ++kt) {
      kb[kt][0] = *(short8*)((char*)Ks + swz(kt * 16 + lr, g * 16));
      kb[kt][1] = *(short8*)((char*)Ks + swz(kt * 16 + lr, 64 + g * 16));
    }
#pragma unroll
    for (int dt = 0; dt < 4; ++dt) {
      vb[dt][0] = *(short8*)((char*)Vs + swz(dt * 16 + lr, g * 16));
      vb[dt][1] = *(short8*)((char*)Vs + swz(dt * 16 + lr, 64 + g * 16));
    }

    // ---- QK^T + online softmax + P writes ----
#pragma unroll
    for (int mt = 0; mt < 2; ++mt) {
      floatx4 s[4];
#pragma unroll
      for (int kt = 0; kt < 4; ++kt) {
        floatx4 z = 0;
        z = __builtin_amdgcn_mfma_f32_16x16x32_bf16(aq[mt][0], kb[kt][0], z, 0, 0, 0);
        z = __builtin_amdgcn_mfma_f32_16x16x32_bf16(aq[mt][1], kb[kt][1], z, 0, 0, 0);
        s[kt] = z;
      }
#pragma unroll
      for (int j = 0; j < 4; ++j) {
        float tm = fmaxf(fmaxf(s[0][j], s[1][j]), fmaxf(s[2][j], s[3][j]));
        for (int off = 8; off >= 1; off >>= 1)
          tm = fmaxf(tm, __shfl_xor(tm, off, 16));
        float mn = fmaxf(m2[mt][j], tm * c2);
        float cf = __builtin_amdgcn_exp2f(m2[mt][j] - mn);
        m2[mt][j] = mn;
        float ts = 0.f;
#pragma unroll
        for (int kt = 0; kt < 4; ++kt) {
          float p = __builtin_amdgcn_exp2f(s[kt][j] * c2 - mn);
          ts += p;
          *(short*)((char*)Pw + swz(mt * 16 + 4 * g + j, (kt * 16 + lr) * 2)) = f2bf(p);
        }
        ellp[mt][j] = ellp[mt][j] * cf + ts;  // per-lane partial; reduce at end
#pragma unroll
        for (int dt = 0; dt < 4; ++dt) acc[mt][dt][j] *= cf;
      }
    }
    __syncthreads();  // P writes before pa reads

    // ---- PV ----
#pragma unroll
    for (int mt = 0; mt < 2; ++mt) {
      short8 pa0 = *(short8*)((char*)Pw + swz(mt * 16 + lr, g * 16));
      short8 pa1 = *(short8*)((char*)Pw + swz(mt * 16 + lr, 64 + g * 16));
#pragma unroll
      for (int dt = 0; dt < 4; ++dt) {
        acc[mt][dt] = __builtin_amdgcn_mfma_f32_16x16x32_bf16(pa0, vb[dt][0], acc[mt][dt], 0, 0, 0);
        acc[mt][dt] = __builtin_amdgcn_mfma_f32_16x16x32_bf16(pa1, vb[dt][1], acc[mt][dt], 0, 0, 0);
      }
    }
    // next iter's staging (Ks/Vs) vs this iter's kb/vb reads: separated by
    // the P-barrier above; its P writes vs this iter's pa reads: separated
    // by its stage-barrier. All hazards barriered (round-3-proven).
  }

  // epilogue: reduce ellp across the 16 lr lanes, write O (bf16)
  const int bb = bh >> 3, h = bh & 7;
#pragma unroll
  for (int mt = 0; mt < 2; ++mt) {
#pragma unroll
    for (int j = 0; j < 4; ++j) {
      float e = ellp[mt][j];
      e += __shfl_xor(e, 1);
      e += __shfl_xor(e, 2);
      e += __shfl_xor(e, 4);
      e += __shfl_xor(e, 8);
      float rl = 1.0f / e;
      int trow = q0 + w * 32 + mt * 16 + 4 * g + j;
      long ob = ((long)(bb * T + trow)) * EMB + h * 64;
#pragma unroll
      for (int dt = 0; dt < 4; ++dt)
        o_ws[ob + dt * 16 + lr] = f2bf(acc[mt][dt][j] * rl);
    }
  }
}

// ---------------------------------------------------------------------------
// Kernel C (unchanged): out[8192][512] = O @ Wu^T + bu (f32 out)
// ---------------------------------------------------------------------------
__global__ __launch_bounds__(256) void proj_kernel(
    const short* __restrict__ o_ws, const float* __restrict__ Wu,
    const float* __restrict__ bu, float* __restrict__ out) {
  __shared__ __align__(16) short As[64 * 64];
  __shared__ __align__(16) short Bs[64 * 64];
  const int tid = threadIdx.x;
  const int lane = tid & 63, w = tid >> 6;
  const int g = lane >> 4, lr = lane & 15;
  const int m0 = blockIdx.x * 64;
  const int n0 = blockIdx.y * 64;

  floatx4 acc[4];
  for (int nt = 0; nt < 4; ++nt) acc[nt] = 0;

  for (int kc = 0; kc < EMB; kc += 64) {
    {
      int row = tid >> 2, kp = (tid & 3) * 16;
      const short8* src = (const short8*)(o_ws + (long)(m0 + row) * EMB + kc + kp);
      short8 v0 = src[0], v1 = src[1];
      *(short8*)((char*)As + swz(row, kp * 2)) = v0;
      *(short8*)((char*)As + swz(row, kp * 2 + 16)) = v1;
    }
    {
      int n = tid >> 2, kp = (tid & 3) * 16;
      const float4* src = (const float4*)(Wu + (long)(n0 + n) * EMB + kc + kp);
      *(short8*)((char*)Bs + swz(n, kp * 2)) = pack8(src[0], src[1]);
      *(short8*)((char*)Bs + swz(n, kp * 2 + 16)) = pack8(src[2], src[3]);
    }
    __syncthreads();

    int arow = w * 16 + lr;
    short8 a0 = *(short8*)((char*)As + swz(arow, g * 16));
    short8 a1 = *(short8*)((char*)As + swz(arow, 64 + g * 16));
    for (int nt = 0; nt < 4; ++nt) {
      int n = nt * 16 + lr;
      short8 b0 = *(short8*)((char*)Bs + swz(n, g * 16));
      short8 b1 = *(short8*)((char*)Bs + swz(n, 64 + g * 16));
      acc[nt] = __builtin_amdgcn_mfma_f32_16x16x32_bf16(a0, b0, acc[nt], 0, 0, 0);
      acc[nt] = __builtin_amdgcn_mfma_f32_16x16x32_bf16(a1, b1, acc[nt], 0, 0, 0);
    }
    __syncthreads();
  }

  for (int nt = 0; nt < 4; ++nt) {
    float bias = bu[n0 + nt * 16 + lr];
    for (int j = 0; j < 4; ++j) {
      int mrow = m0 + w * 16 + 4 * g + j;
      out[(long)mrow * EMB + n0 + nt * 16 + lr] = acc[nt][j] + bias;
    }
  }
}

extern "C" void kernel_launch(void* const* d_in, const int* in_sizes, int n_in,
                              void* d_out, int out_size, void* d_ws, size_t ws_size,
                              hipStream_t stream) {
  const float* x  = (const float*)d_in[0];
  const float* Wq = (const float*)d_in[1];
  const float* Wk = (const float*)d_in[2];
  const float* Wv = (const float*)d_in[3];
  const float* Wu = (const float*)d_in[4];
  const float* bu = (const float*)d_in[5];
  float* out = (float*)d_out;

  const long per = (long)BH * T * 64;
  short* q_ws  = (short*)d_ws;
  short* k_ws  = q_ws + per;
  short* vt_ws = k_ws + per;   // [bh][d][t]
  short* o_ws  = vt_ws + per;  // [8192][512] bf16

  qkv_kernel<<<256, 256, 0, stream>>>(x, Wq, Wk, Wv, q_ws, k_ws, vt_ws);
  attn_kernel<<<dim3(T / 128, BH), 256, 0, stream>>>(q_ws, k_ws, vt_ws, o_ws);
  proj_kernel<<<dim3(BATCH * T / 64, EMB / 64), 256, 0, stream>>>(o_ws, Wu, bu, out);
}

// Round 7
// 175.529 us; speedup vs baseline: 2.4517x; 1.3415x over previous
//
#include <hip/hip_runtime.h>
#include <hip/hip_bf16.h>

// b=2, t=4096, emb=512, heads=8, head_dim=64.
// out = softmax((xWq^T)(xWk^T)^T / sqrt(512)) (xWv^T) Wu^T + bu
// Round 6: round 5 with the v_cvt_pk_bf16_f32 inline asm replaced by explicit
// f2bf short4 packing. cvt_pk was the only element shared by all failing
// rounds (1,2,5) and absent from all passing rounds (0,3,4); its pack order
// was an unverified assumption. Swapped QK^T + const-bias no-max softmax +
// b64 P writes + per-lane ell retained (all proven sound against round-0/4
// passes + m89's C/D layout).

#define T 4096
#define HEADS 8
#define HD 64
#define EMB 512
#define BATCH 2
#define BH (BATCH * HEADS)

typedef __attribute__((ext_vector_type(8))) short short8;
typedef __attribute__((ext_vector_type(4))) short short4v;
typedef __attribute__((ext_vector_type(4))) float floatx4;

// f32 -> bf16 round-to-nearest-even
__device__ inline short f2bf(float f) {
  union { float f; unsigned u; } v; v.f = f;
  unsigned r = v.u + 0x7FFF + ((v.u >> 16) & 1);
  return (short)(r >> 16);
}

__device__ inline short8 pack8(float4 a, float4 b) {
  short8 o;
  o[0] = f2bf(a.x); o[1] = f2bf(a.y); o[2] = f2bf(a.z); o[3] = f2bf(a.w);
  o[4] = f2bf(b.x); o[5] = f2bf(b.y); o[6] = f2bf(b.z); o[7] = f2bf(b.w);
  return o;
}

// swizzled byte offset in a [rows][64] bf16 tile (row stride 128B)
__device__ inline int swz(int row, int byte) {
  return (row * 128 + byte) ^ ((row & 7) << 4);
}

// ---------------------------------------------------------------------------
// Kernel A (round-4 verbatim): q,k -> [bh][t][d]; v -> vt[bh][d][t] transposed.
// ---------------------------------------------------------------------------
__global__ __launch_bounds__(256) void qkv_kernel(
    const float* __restrict__ x, const float* __restrict__ Wq,
    const float* __restrict__ Wk, const float* __restrict__ Wv,
    short* __restrict__ q_ws, short* __restrict__ k_ws, short* __restrict__ vt_ws) {
  __shared__ __align__(16) short xs[256 * 64];
  const int tid = threadIdx.x;
  const int lane = tid & 63;
  const int w = tid >> 6;
  const int g = lane >> 4, lr = lane & 15;
  const long rowbase = (long)blockIdx.x * 256;

  {
    const float4* xv = (const float4*)(x + (rowbase + tid) * 64);
    for (int c = 0; c < 8; ++c) {
      float4 a = xv[2 * c], b = xv[2 * c + 1];
      *(short8*)((char*)xs + swz(tid, c * 16)) = pack8(a, b);
    }
  }
  __syncthreads();

  const float* Ws[3] = {Wq, Wk, Wv};
  for (int m = 0; m < 3; ++m) {
    const float* W = Ws[m];
    for (int nt = 0; nt < 4; ++nt) {
      const int coln = nt * 16 + lr;
      const float4* wr0 = (const float4*)(W + coln * 64 + 8 * g);
      const float4* wr1 = (const float4*)(W + coln * 64 + 32 + 8 * g);
      short8 b0 = pack8(wr0[0], wr0[1]);
      short8 b1 = pack8(wr1[0], wr1[1]);
      for (int mr = 0; mr < 4; ++mr) {
        const int arow = w * 64 + mr * 16 + lr;
        short8 a0 = *(short8*)((char*)xs + swz(arow, g * 16));
        short8 a1 = *(short8*)((char*)xs + swz(arow, 64 + g * 16));
        floatx4 acc = 0;
        acc = __builtin_amdgcn_mfma_f32_16x16x32_bf16(a0, b0, acc, 0, 0, 0);
        acc = __builtin_amdgcn_mfma_f32_16x16x32_bf16(a1, b1, acc, 0, 0, 0);
        for (int jj = 0; jj < 4; ++jj) {
          long R = rowbase + w * 64 + mr * 16 + 4 * g + jj;
          int bb = (int)(R >> 15);
          int h = (int)(R & 7);
          int t = (int)((R >> 3) & 4095);
          if (m == 0)
            q_ws[(((long)(bb * HEADS + h) * T + t) * 64) + coln] = f2bf(acc[jj]);
          else if (m == 1)
            k_ws[(((long)(bb * HEADS + h) * T + t) * 64) + coln] = f2bf(acc[jj]);
          else
            vt_ws[((long)(bb * HEADS + h) * 64 + coln) * T + t] = f2bf(acc[jj]);
        }
      }
    }
  }
}

// ---------------------------------------------------------------------------
// Kernel B: attention. 32 q-rows/wave, 128/block, grid 512 (2 blocks/CU).
// Swapped QK^T: s[kt] = mfma(kb, aq) -> lane (g,lr) holds S[q=mt*16+lr]
// [key=16kt+4g+j] (j=reg). p = exp2(s*c2 - 3) (no-max). P packed as short4
// (explicit f2bf, byte-order certain) -> one b64 write per (mt,kt).
// ---------------------------------------------------------------------------
__global__ __launch_bounds__(256) void attn_kernel(
    const short* __restrict__ q_ws, const short* __restrict__ k_ws,
    const short* __restrict__ vt_ws, short* __restrict__ o_ws) {
  __shared__ __align__(16) short Ks[64 * 64];       // [key][d] swizzled
  __shared__ __align__(16) short Vs[64 * 64];       // [d][key] swizzled
  __shared__ __align__(16) short Ps[4][32 * 64];    // per-wave P [q_local][key] swizzled
  const int tid = threadIdx.x, lane = tid & 63, w = tid >> 6;
  const int g = lane >> 4, lr = lane & 15;
  const int bh = blockIdx.y;
  const int q0 = blockIdx.x * 128;
  const short* Qp = q_ws + (long)bh * T * 64;
  const short* Kp = k_ws + (long)bh * T * 64;
  const short* Vt = vt_ws + (long)bh * 64 * T;
  short* Pw = (short*)Ps[w];

  const float c2 = 0.0441941738241592f * 1.4426950408889634f;  // scale * log2(e)

  // Q fragments (used as MFMA B operand after the swap; same registers)
  short8 aq[2][2];
#pragma unroll
  for (int mt = 0; mt < 2; ++mt) {
    int r = q0 + w * 32 + mt * 16 + lr;
    aq[mt][0] = *(const short8*)(Qp + (long)r * 64 + g * 8);
    aq[mt][1] = *(const short8*)(Qp + (long)r * 64 + 32 + g * 8);
  }

  floatx4 acc[2][4];  // [mt][dt]; C rows = q_local 4g+j, cols = d dt*16+lr
#pragma unroll
  for (int mt = 0; mt < 2; ++mt)
#pragma unroll
    for (int dt = 0; dt < 4; ++dt) acc[mt][dt] = 0;
  float ellp[2] = {0.f, 0.f};  // per-lane partial row-sum for q-row mt*16+lr

  const int srow = tid >> 2;          // 0..63
  const int sseg = (tid & 3) * 16;    // element offset in row

  for (int kv = 0; kv < T; kv += 64) {
    // ---- stage K tile [key][d] and V tile [d][key] (b128 copies) ----
    {
      const short8* ksrc = (const short8*)(Kp + (long)(kv + srow) * 64 + sseg);
      short8 k0 = ksrc[0], k1 = ksrc[1];
      const short8* vsrc = (const short8*)(Vt + (long)srow * T + kv + sseg);
      short8 v0 = vsrc[0], v1 = vsrc[1];
      *(short8*)((char*)Ks + swz(srow, sseg * 2)) = k0;
      *(short8*)((char*)Ks + swz(srow, sseg * 2 + 16)) = k1;
      *(short8*)((char*)Vs + swz(srow, sseg * 2)) = v0;
      *(short8*)((char*)Vs + swz(srow, sseg * 2 + 16)) = v1;
    }
    __syncthreads();

    // ---- phase A: fragment loads, swapped QK^T, exp2, packed P writes ----
    short8 kb[4][2], vb[4][2];
#pragma unroll
    for (int kt = 0; kt < 4; ++kt) {
      kb[kt][0] = *(short8*)((char*)Ks + swz(kt * 16 + lr, g * 16));
      kb[kt][1] = *(short8*)((char*)Ks + swz(kt * 16 + lr, 64 + g * 16));
    }
#pragma unroll
    for (int dt = 0; dt < 4; ++dt) {
      vb[dt][0] = *(short8*)((char*)Vs + swz(dt * 16 + lr, g * 16));
      vb[dt][1] = *(short8*)((char*)Vs + swz(dt * 16 + lr, 64 + g * 16));
    }

#pragma unroll
    for (int mt = 0; mt < 2; ++mt) {
      floatx4 s[4];
#pragma unroll
      for (int kt = 0; kt < 4; ++kt) {
        floatx4 z = 0;
        // swapped: A = K fragment, B = Q fragment -> C[key][q]
        z = __builtin_amdgcn_mfma_f32_16x16x32_bf16(kb[kt][0], aq[mt][0], z, 0, 0, 0);
        z = __builtin_amdgcn_mfma_f32_16x16x32_bf16(kb[kt][1], aq[mt][1], z, 0, 0, 0);
        s[kt] = z;
      }
#pragma unroll
      for (int kt = 0; kt < 4; ++kt) {
        // lane holds keys 16kt+4g+{0..3} for q-row mt*16+lr
        float p0 = __builtin_amdgcn_exp2f(fmaf(s[kt][0], c2, -3.0f));
        float p1 = __builtin_amdgcn_exp2f(fmaf(s[kt][1], c2, -3.0f));
        float p2 = __builtin_amdgcn_exp2f(fmaf(s[kt][2], c2, -3.0f));
        float p3 = __builtin_amdgcn_exp2f(fmaf(s[kt][3], c2, -3.0f));
        ellp[mt] += (p0 + p1) + (p2 + p3);
        short4v pk;
        pk[0] = f2bf(p0); pk[1] = f2bf(p1); pk[2] = f2bf(p2); pk[3] = f2bf(p3);
        *(short4v*)((char*)Pw + swz(mt * 16 + lr, 32 * kt + 8 * g)) = pk;
      }
    }
    __syncthreads();  // P writes before pa reads

    // ---- phase B: PV (registers + Ps only; Ks/Vs free for next stage) ----
#pragma unroll
    for (int mt = 0; mt < 2; ++mt) {
      short8 pa0 = *(short8*)((char*)Pw + swz(mt * 16 + lr, g * 16));
      short8 pa1 = *(short8*)((char*)Pw + swz(mt * 16 + lr, 64 + g * 16));
#pragma unroll
      for (int dt = 0; dt < 4; ++dt) {
        acc[mt][dt] = __builtin_amdgcn_mfma_f32_16x16x32_bf16(pa0, vb[dt][0], acc[mt][dt], 0, 0, 0);
        acc[mt][dt] = __builtin_amdgcn_mfma_f32_16x16x32_bf16(pa1, vb[dt][1], acc[mt][dt], 0, 0, 0);
      }
    }
    // next iter: stage writes Ks/Vs (this iter's Ks/Vs reads all in phase A,
    // behind the mid-barrier); its P writes behind its stage-barrier. Safe.
  }

  // ---- epilogue ----
  // ellp[mt] covers keys {16kt+4g+j} for q-row mt*16+lr; sum across g-groups:
  float ef[2];
#pragma unroll
  for (int mt = 0; mt < 2; ++mt) {
    float e = ellp[mt];
    e += __shfl_xor(e, 16);
    e += __shfl_xor(e, 32);
    ef[mt] = e;  // every lane with this lr now holds full sum for its q-row
  }
  const int bb = bh >> 3, h = bh & 7;
#pragma unroll
  for (int mt = 0; mt < 2; ++mt) {
#pragma unroll
    for (int j = 0; j < 4; ++j) {
      // acc row q_local = 4g+j; its ell lives at lane lr'=4g+j
      float rl = 1.0f / __shfl(ef[mt], 4 * g + j);
      int trow = q0 + w * 32 + mt * 16 + 4 * g + j;
      long ob = ((long)(bb * T + trow)) * EMB + h * 64;
#pragma unroll
      for (int dt = 0; dt < 4; ++dt)
        o_ws[ob + dt * 16 + lr] = f2bf(acc[mt][dt][j] * rl);
    }
  }
}

// ---------------------------------------------------------------------------
// Kernel C (round-4 verbatim): out[8192][512] = O @ Wu^T + bu (f32 out)
// ---------------------------------------------------------------------------
__global__ __launch_bounds__(256) void proj_kernel(
    const short* __restrict__ o_ws, const float* __restrict__ Wu,
    const float* __restrict__ bu, float* __restrict__ out) {
  __shared__ __align__(16) short As[64 * 64];
  __shared__ __align__(16) short Bs[64 * 64];
  const int tid = threadIdx.x;
  const int lane = tid & 63, w = tid >> 6;
  const int g = lane >> 4, lr = lane & 15;
  const int m0 = blockIdx.x * 64;
  const int n0 = blockIdx.y * 64;

  floatx4 acc[4];
  for (int nt = 0; nt < 4; ++nt) acc[nt] = 0;

  for (int kc = 0; kc < EMB; kc += 64) {
    {
      int row = tid >> 2, kp = (tid & 3) * 16;
      const short8* src = (const short8*)(o_ws + (long)(m0 + row) * EMB + kc + kp);
      short8 v0 = src[0], v1 = src[1];
      *(short8*)((char*)As + swz(row, kp * 2)) = v0;
      *(short8*)((char*)As + swz(row, kp * 2 + 16)) = v1;
    }
    {
      int n = tid >> 2, kp = (tid & 3) * 16;
      const float4* src = (const float4*)(Wu + (long)(n0 + n) * EMB + kc + kp);
      *(short8*)((char*)Bs + swz(n, kp * 2)) = pack8(src[0], src[1]);
      *(short8*)((char*)Bs + swz(n, kp * 2 + 16)) = pack8(src[2], src[3]);
    }
    __syncthreads();

    int arow = w * 16 + lr;
    short8 a0 = *(short8*)((char*)As + swz(arow, g * 16));
    short8 a1 = *(short8*)((char*)As + swz(arow, 64 + g * 16));
    for (int nt = 0; nt < 4; ++nt) {
      int n = nt * 16 + lr;
      short8 b0 = *(short8*)((char*)Bs + swz(n, g * 16));
      short8 b1 = *(short8*)((char*)Bs + swz(n, 64 + g * 16));
      acc[nt] = __builtin_amdgcn_mfma_f32_16x16x32_bf16(a0, b0, acc[nt], 0, 0, 0);
      acc[nt] = __builtin_amdgcn_mfma_f32_16x16x32_bf16(a1, b1, acc[nt], 0, 0, 0);
    }
    __syncthreads();
  }

  for (int nt = 0; nt < 4; ++nt) {
    float bias = bu[n0 + nt * 16 + lr];
    for (int j = 0; j < 4; ++j) {
      int mrow = m0 + w * 16 + 4 * g + j;
      out[(long)mrow * EMB + n0 + nt * 16 + lr] = acc[nt][j] + bias;
    }
  }
}

extern "C" void kernel_launch(void* const* d_in, const int* in_sizes, int n_in,
                              void* d_out, int out_size, void* d_ws, size_t ws_size,
                              hipStream_t stream) {
  const float* x  = (const float*)d_in[0];
  const float* Wq = (const float*)d_in[1];
  const float* Wk = (const float*)d_in[2];
  const float* Wv = (const float*)d_in[3];
  const float* Wu = (const float*)d_in[4];
  const float* bu = (const float*)d_in[5];
  float* out = (float*)d_out;

  const long per = (long)BH * T * 64;
  short* q_ws  = (short*)d_ws;
  short* k_ws  = q_ws + per;
  short* vt_ws = k_ws + per;   // [bh][d][t]
  short* o_ws  = vt_ws + per;  // [8192][512] bf16

  qkv_kernel<<<256, 256, 0, stream>>>(x, Wq, Wk, Wv, q_ws, k_ws, vt_ws);
  attn_kernel<<<dim3(T / 128, BH), 256, 0, stream>>>(q_ws, k_ws, vt_ws, o_ws);
  proj_kernel<<<dim3(BATCH * T / 64, EMB / 64), 256, 0, stream>>>(o_ws, Wu, bu, out);
}

// Round 8
// 132.204 us; speedup vs baseline: 3.2552x; 1.3277x over previous
//
#include <hip/hip_runtime.h>
#include <hip/hip_bf16.h>

// b=2, t=4096, emb=512, heads=8, head_dim=64.
// out = softmax((xWq^T)(xWk^T)^T / sqrt(512)) (xWv^T) Wu^T + bu
// Round 7: in-register P. Swapped QK^T leaves each lane holding P[q=lr]
// [keys 16kt+4g+reg]; defining the PV k-slot order p=8g+4kt+reg (a bijection,
// cancels in the MFMA sum) makes those 16 values exactly the two PV
// A-fragments. V is stored key-permuted within 32-blocks in qkv so the vb
// LDS reads are unchanged. Deletes the P LDS round-trip (+its 4.19M bank
// conflicts) and one barrier (Ks/Vs double-buffered, single sync/iter).
// bf16 pack via __float22bfloat162_rn (compiler cvt_pk, defined order).

#define T 4096
#define HEADS 8
#define HD 64
#define EMB 512
#define BATCH 2
#define BH (BATCH * HEADS)

typedef __attribute__((ext_vector_type(8))) short short8;
typedef __attribute__((ext_vector_type(4))) float floatx4;

// f32 -> bf16 round-to-nearest-even (host-side-proven bit trick)
__device__ inline short f2bf(float f) {
  union { float f; unsigned u; } v; v.f = f;
  unsigned r = v.u + 0x7FFF + ((v.u >> 16) & 1);
  return (short)(r >> 16);
}

__device__ inline short8 pack8(float4 a, float4 b) {
  short8 o;
  o[0] = f2bf(a.x); o[1] = f2bf(a.y); o[2] = f2bf(a.z); o[3] = f2bf(a.w);
  o[4] = f2bf(b.x); o[5] = f2bf(b.y); o[6] = f2bf(b.z); o[7] = f2bf(b.w);
  return o;
}

// 8 floats -> short8 of bf16 via compiler-generated v_cvt_pk_bf16_f32
__device__ inline short8 packbf(float p0, float p1, float p2, float p3,
                                float p4, float p5, float p6, float p7) {
  union { __hip_bfloat162 h[4]; short8 s; } u;
  float2 t;
  t.x = p0; t.y = p1; u.h[0] = __float22bfloat162_rn(t);
  t.x = p2; t.y = p3; u.h[1] = __float22bfloat162_rn(t);
  t.x = p4; t.y = p5; u.h[2] = __float22bfloat162_rn(t);
  t.x = p6; t.y = p7; u.h[3] = __float22bfloat162_rn(t);
  return u.s;
}

// swizzled byte offset in a [rows][64] bf16 tile (row stride 128B)
__device__ inline int swz(int row, int byte) {
  return (row * 128 + byte) ^ ((row & 7) << 4);
}

// ---------------------------------------------------------------------------
// Kernel A: q,k -> [bh][t][d]; v -> vt[bh][d][t''] transposed with keys
// permuted within each 32-block: t'' = (t&~31)|((t>>2)&3)<<3|((t>>4)&1)<<2|(t&3)
// (slot p=8g+4kt+reg holds key 16kt+4g+reg, matching the PV fragment order).
// ---------------------------------------------------------------------------
__global__ __launch_bounds__(256) void qkv_kernel(
    const float* __restrict__ x, const float* __restrict__ Wq,
    const float* __restrict__ Wk, const float* __restrict__ Wv,
    short* __restrict__ q_ws, short* __restrict__ k_ws, short* __restrict__ vt_ws) {
  __shared__ __align__(16) short xs[256 * 64];
  const int tid = threadIdx.x;
  const int lane = tid & 63;
  const int w = tid >> 6;
  const int g = lane >> 4, lr = lane & 15;
  const long rowbase = (long)blockIdx.x * 256;

  {
    const float4* xv = (const float4*)(x + (rowbase + tid) * 64);
    for (int c = 0; c < 8; ++c) {
      float4 a = xv[2 * c], b = xv[2 * c + 1];
      *(short8*)((char*)xs + swz(tid, c * 16)) = pack8(a, b);
    }
  }
  __syncthreads();

  const float* Ws[3] = {Wq, Wk, Wv};
  for (int m = 0; m < 3; ++m) {
    const float* W = Ws[m];
    for (int nt = 0; nt < 4; ++nt) {
      const int coln = nt * 16 + lr;
      const float4* wr0 = (const float4*)(W + coln * 64 + 8 * g);
      const float4* wr1 = (const float4*)(W + coln * 64 + 32 + 8 * g);
      short8 b0 = pack8(wr0[0], wr0[1]);
      short8 b1 = pack8(wr1[0], wr1[1]);
      for (int mr = 0; mr < 4; ++mr) {
        const int arow = w * 64 + mr * 16 + lr;
        short8 a0 = *(short8*)((char*)xs + swz(arow, g * 16));
        short8 a1 = *(short8*)((char*)xs + swz(arow, 64 + g * 16));
        floatx4 acc = 0;
        acc = __builtin_amdgcn_mfma_f32_16x16x32_bf16(a0, b0, acc, 0, 0, 0);
        acc = __builtin_amdgcn_mfma_f32_16x16x32_bf16(a1, b1, acc, 0, 0, 0);
        for (int jj = 0; jj < 4; ++jj) {
          long R = rowbase + w * 64 + mr * 16 + 4 * g + jj;
          int bb = (int)(R >> 15);
          int h = (int)(R & 7);
          int t = (int)((R >> 3) & 4095);
          if (m == 0)
            q_ws[(((long)(bb * HEADS + h) * T + t) * 64) + coln] = f2bf(acc[jj]);
          else if (m == 1)
            k_ws[(((long)(bb * HEADS + h) * T + t) * 64) + coln] = f2bf(acc[jj]);
          else {
            int tp = (t & ~31) | (((t >> 2) & 3) << 3) | (((t >> 4) & 1) << 2) | (t & 3);
            vt_ws[((long)(bb * HEADS + h) * 64 + coln) * T + tp] = f2bf(acc[jj]);
          }
        }
      }
    }
  }
}

// ---------------------------------------------------------------------------
// Kernel B: attention. 32 q-rows/wave, 128/block, grid 512 (2 blocks/CU).
// Swapped QK^T -> lane (g,lr) holds S[q=lr][keys 16kt+4g+reg]. exp2 in-reg,
// pack to pa0/pa1 (PV A-fragments, slot order p=8g+4kt+reg), PV directly.
// Ks/Vs double-buffered, ONE barrier per iteration. No P LDS buffer.
// ---------------------------------------------------------------------------
__global__ __launch_bounds__(256) void attn_kernel(
    const short* __restrict__ q_ws, const short* __restrict__ k_ws,
    const short* __restrict__ vt_ws, short* __restrict__ o_ws) {
  __shared__ __align__(16) short Ks[2][64 * 64];    // [key][d] swizzled
  __shared__ __align__(16) short Vs[2][64 * 64];    // [d][key-slot] swizzled
  const int tid = threadIdx.x, lane = tid & 63, w = tid >> 6;
  const int g = lane >> 4, lr = lane & 15;
  const int bh = blockIdx.y;
  const int q0 = blockIdx.x * 128;
  const short* Qp = q_ws + (long)bh * T * 64;
  const short* Kp = k_ws + (long)bh * T * 64;
  const short* Vt = vt_ws + (long)bh * 64 * T;

  const float c2 = 0.0441941738241592f * 1.4426950408889634f;  // scale * log2(e)

  short8 aq[2][2];
#pragma unroll
  for (int mt = 0; mt < 2; ++mt) {
    int r = q0 + w * 32 + mt * 16 + lr;
    aq[mt][0] = *(const short8*)(Qp + (long)r * 64 + g * 8);
    aq[mt][1] = *(const short8*)(Qp + (long)r * 64 + 32 + g * 8);
  }

  floatx4 acc[2][4];  // [mt][dt]; rows = q_local 4g+j, cols = d dt*16+lr
#pragma unroll
  for (int mt = 0; mt < 2; ++mt)
#pragma unroll
    for (int dt = 0; dt < 4; ++dt) acc[mt][dt] = 0;
  float ellp[2] = {0.f, 0.f};

  const int srow = tid >> 2;          // 0..63
  const int sseg = (tid & 3) * 16;    // element offset in row

  // prologue: stage tile 0 into buffer 0
  {
    const short8* ksrc = (const short8*)(Kp + (long)srow * 64 + sseg);
    short8 k0 = ksrc[0], k1 = ksrc[1];
    const short8* vsrc = (const short8*)(Vt + (long)srow * T + sseg);
    short8 v0 = vsrc[0], v1 = vsrc[1];
    *(short8*)((char*)Ks[0] + swz(srow, sseg * 2)) = k0;
    *(short8*)((char*)Ks[0] + swz(srow, sseg * 2 + 16)) = k1;
    *(short8*)((char*)Vs[0] + swz(srow, sseg * 2)) = v0;
    *(short8*)((char*)Vs[0] + swz(srow, sseg * 2 + 16)) = v1;
  }
  __syncthreads();

  for (int it = 0; it < T / 64; ++it) {
    const int cur = it & 1;
    const int nk = ((it + 1) & (T / 64 - 1)) * 64;
    // prefetch next tile into registers (latency hides under compute)
    const short8* ksrc = (const short8*)(Kp + (long)(nk + srow) * 64 + sseg);
    short8 nk0 = ksrc[0], nk1 = ksrc[1];
    const short8* vsrc = (const short8*)(Vt + (long)srow * T + nk + sseg);
    short8 nv0 = vsrc[0], nv1 = vsrc[1];

    char* KsB = (char*)Ks[cur];
    char* VsB = (char*)Vs[cur];

    // ---- fragment loads ----
    short8 kb[4][2], vb[4][2];
#pragma unroll
    for (int kt = 0; kt < 4; ++kt) {
      kb[kt][0] = *(short8*)(KsB + swz(kt * 16 + lr, g * 16));
      kb[kt][1] = *(short8*)(KsB + swz(kt * 16 + lr, 64 + g * 16));
    }
#pragma unroll
    for (int dt = 0; dt < 4; ++dt) {
      vb[dt][0] = *(short8*)(VsB + swz(dt * 16 + lr, g * 16));
      vb[dt][1] = *(short8*)(VsB + swz(dt * 16 + lr, 64 + g * 16));
    }

    // ---- QK^T + softmax + PV, fully per-wave, P in registers ----
#pragma unroll
    for (int mt = 0; mt < 2; ++mt) {
      floatx4 s[4];
#pragma unroll
      for (int kt = 0; kt < 4; ++kt) {
        floatx4 z = 0;
        z = __builtin_amdgcn_mfma_f32_16x16x32_bf16(kb[kt][0], aq[mt][0], z, 0, 0, 0);
        z = __builtin_amdgcn_mfma_f32_16x16x32_bf16(kb[kt][1], aq[mt][1], z, 0, 0, 0);
        s[kt] = z;
      }
      float p[16];
#pragma unroll
      for (int kt = 0; kt < 4; ++kt) {
#pragma unroll
        for (int r = 0; r < 4; ++r)
          p[kt * 4 + r] = __builtin_amdgcn_exp2f(fmaf(s[kt][r], c2, -3.0f));
      }
#pragma unroll
      for (int e = 0; e < 16; ++e) ellp[mt] += p[e];
      // PV A-fragments: slot p=8g+4kt+reg -> element j=4kt+reg of half g
      short8 pa0 = packbf(p[0], p[1], p[2], p[3], p[4], p[5], p[6], p[7]);
      short8 pa1 = packbf(p[8], p[9], p[10], p[11], p[12], p[13], p[14], p[15]);
#pragma unroll
      for (int dt = 0; dt < 4; ++dt) {
        acc[mt][dt] = __builtin_amdgcn_mfma_f32_16x16x32_bf16(pa0, vb[dt][0], acc[mt][dt], 0, 0, 0);
        acc[mt][dt] = __builtin_amdgcn_mfma_f32_16x16x32_bf16(pa1, vb[dt][1], acc[mt][dt], 0, 0, 0);
      }
    }

    // ---- write prefetched tile to the other buffer ----
    char* KsN = (char*)Ks[cur ^ 1];
    char* VsN = (char*)Vs[cur ^ 1];
    *(short8*)(KsN + swz(srow, sseg * 2)) = nk0;
    *(short8*)(KsN + swz(srow, sseg * 2 + 16)) = nk1;
    *(short8*)(VsN + swz(srow, sseg * 2)) = nv0;
    *(short8*)(VsN + swz(srow, sseg * 2 + 16)) = nv1;
    __syncthreads();
    // hazards: writes hit buf[cur^1] (nobody reads it this iter); next iter's
    // reads of buf[cur^1] are behind this barrier; next iter's writes hit
    // buf[cur], whose reads completed before this barrier. Single sync OK.
  }

  // ---- epilogue: reduce ellp across g-groups, normalize, store ----
  float ef[2];
#pragma unroll
  for (int mt = 0; mt < 2; ++mt) {
    float e = ellp[mt];
    e += __shfl_xor(e, 16);
    e += __shfl_xor(e, 32);
    ef[mt] = e;
  }
  const int bb = bh >> 3, h = bh & 7;
#pragma unroll
  for (int mt = 0; mt < 2; ++mt) {
#pragma unroll
    for (int j = 0; j < 4; ++j) {
      float rl = 1.0f / __shfl(ef[mt], 4 * g + j);
      int trow = q0 + w * 32 + mt * 16 + 4 * g + j;
      long ob = ((long)(bb * T + trow)) * EMB + h * 64;
#pragma unroll
      for (int dt = 0; dt < 4; ++dt)
        o_ws[ob + dt * 16 + lr] = f2bf(acc[mt][dt][j] * rl);
    }
  }
}

// ---------------------------------------------------------------------------
// Kernel C (verbatim): out[8192][512] = O @ Wu^T + bu (f32 out)
// ---------------------------------------------------------------------------
__global__ __launch_bounds__(256) void proj_kernel(
    const short* __restrict__ o_ws, const float* __restrict__ Wu,
    const float* __restrict__ bu, float* __restrict__ out) {
  __shared__ __align__(16) short As[64 * 64];
  __shared__ __align__(16) short Bs[64 * 64];
  const int tid = threadIdx.x;
  const int lane = tid & 63, w = tid >> 6;
  const int g = lane >> 4, lr = lane & 15;
  const int m0 = blockIdx.x * 64;
  const int n0 = blockIdx.y * 64;

  floatx4 acc[4];
  for (int nt = 0; nt < 4; ++nt) acc[nt] = 0;

  for (int kc = 0; kc < EMB; kc += 64) {
    {
      int row = tid >> 2, kp = (tid & 3) * 16;
      const short8* src = (const short8*)(o_ws + (long)(m0 + row) * EMB + kc + kp);
      short8 v0 = src[0], v1 = src[1];
      *(short8*)((char*)As + swz(row, kp * 2)) = v0;
      *(short8*)((char*)As + swz(row, kp * 2 + 16)) = v1;
    }
    {
      int n = tid >> 2, kp = (tid & 3) * 16;
      const float4* src = (const float4*)(Wu + (long)(n0 + n) * EMB + kc + kp);
      *(short8*)((char*)Bs + swz(n, kp * 2)) = pack8(src[0], src[1]);
      *(short8*)((char*)Bs + swz(n, kp * 2 + 16)) = pack8(src[2], src[3]);
    }
    __syncthreads();

    int arow = w * 16 + lr;
    short8 a0 = *(short8*)((char*)As + swz(arow, g * 16));
    short8 a1 = *(short8*)((char*)As + swz(arow, 64 + g * 16));
    for (int nt = 0; nt < 4; ++nt) {
      int n = nt * 16 + lr;
      short8 b0 = *(short8*)((char*)Bs + swz(n, g * 16));
      short8 b1 = *(short8*)((char*)Bs + swz(n, 64 + g * 16));
      acc[nt] = __builtin_amdgcn_mfma_f32_16x16x32_bf16(a0, b0, acc[nt], 0, 0, 0);
      acc[nt] = __builtin_amdgcn_mfma_f32_16x16x32_bf16(a1, b1, acc[nt], 0, 0, 0);
    }
    __syncthreads();
  }

  for (int nt = 0; nt < 4; ++nt) {
    float bias = bu[n0 + nt * 16 + lr];
    for (int j = 0; j < 4; ++j) {
      int mrow = m0 + w * 16 + 4 * g + j;
      out[(long)mrow * EMB + n0 + nt * 16 + lr] = acc[nt][j] + bias;
    }
  }
}

extern "C" void kernel_launch(void* const* d_in, const int* in_sizes, int n_in,
                              void* d_out, int out_size, void* d_ws, size_t ws_size,
                              hipStream_t stream) {
  const float* x  = (const float*)d_in[0];
  const float* Wq = (const float*)d_in[1];
  const float* Wk = (const float*)d_in[2];
  const float* Wv = (const float*)d_in[3];
  const float* Wu = (const float*)d_in[4];
  const float* bu = (const float*)d_in[5];
  float* out = (float*)d_out;

  const long per = (long)BH * T * 64;
  short* q_ws  = (short*)d_ws;
  short* k_ws  = q_ws + per;
  short* vt_ws = k_ws + per;   // [bh][d][t''] (key-permuted within 32-blocks)
  short* o_ws  = vt_ws + per;  // [8192][512] bf16

  qkv_kernel<<<256, 256, 0, stream>>>(x, Wq, Wk, Wv, q_ws, k_ws, vt_ws);
  attn_kernel<<<dim3(T / 128, BH), 256, 0, stream>>>(q_ws, k_ws, vt_ws, o_ws);
  proj_kernel<<<dim3(BATCH * T / 64, EMB / 64), 256, 0, stream>>>(o_ws, Wu, bu, out);
}